// Round 6
// baseline (714.616 us; speedup 1.0000x reference)
//
#include <hip/hip_runtime.h>
#include <math.h>

#define SS 256
#define BB 4
#define HH 256
#define LE 2994
#define LEB (LE*BB)
#define SCALE 0.08838834764831845f  // 1/sqrt(128)

typedef __attribute__((ext_vector_type(8))) short bf16x8;
typedef __attribute__((ext_vector_type(4))) float f32x4;

__device__ inline ushort f2b(float f) {   // fp32 -> bf16 RNE
    unsigned u = __float_as_uint(f);
    u += 0x7FFFu + ((u >> 16) & 1u);
    return (ushort)(u >> 16);
}

// ---------------- init: zero loss/bnsums + edge tables ----------------

__global__ void k_init(float* __restrict__ out, float* __restrict__ bnsums,
                       int* __restrict__ grp, int* __restrict__ idxt) {
    int bid = blockIdx.x, t = threadIdx.x;
    if (bid == 0) {
        if (t == 0) out[0] = 0.f;
        bnsums[t] = 0.f; bnsums[256 + t] = 0.f;
        return;
    }
    int e = (bid - 1) * 256 + t;
    if (e >= LE) return;
    int g, pos;
    if (e < 78) {
        g = (int)((1.0f + sqrtf(8.0f * (float)e + 1.0f)) * 0.5f);
        while (g * (g - 1) / 2 > e) g--;
        while ((g + 1) * g / 2 <= e) g++;
        pos = e - g * (g - 1) / 2;
        idxt[e] = pos;
    } else {
        int r = e - 78;
        g = 13 + r / 12;
        pos = r % 12;
        idxt[e] = g - 12 + pos;
    }
    grp[e] = g;
}

// ---------------- bf16 MFMA GEMM: C[M,N] = A[M,K] @ W[N,K]^T + bias ----------------
// N % 128 == 0, K % 32 == 0. 128x128 tile.

__global__ __launch_bounds__(256) void k_gemm_mfma(
    const float* __restrict__ A, const float* __restrict__ W,
    const float* __restrict__ bias, float* __restrict__ C,
    int M, int N, int K, int relu)
{
    __shared__ ushort As[128 * 32];
    __shared__ ushort Ws[128 * 32];
    int tid = threadIdx.x;
    int wave = tid >> 6, lane = tid & 63;
    int wr = (wave >> 1) * 64, wc = (wave & 1) * 64;
    int m0 = blockIdx.y * 128, n0 = blockIdx.x * 128;
    int q = lane >> 4, p = lane & 15;

    f32x4 acc[4][4];
    #pragma unroll
    for (int i = 0; i < 4; i++)
        #pragma unroll
        for (int j = 0; j < 4; j++) acc[i][j] = (f32x4){0.f, 0.f, 0.f, 0.f};

    int srow = tid >> 1;
    int scol = (tid & 1) << 4;
    const float* Arow = A + (size_t)(m0 + srow) * K + scol;
    const float* Wrow = W + (size_t)(n0 + srow) * K + scol;
    bool aok = (m0 + srow) < M;
    ushort* asd = &As[srow * 32 + scol];
    ushort* wsd = &Ws[srow * 32 + scol];

    for (int k0 = 0; k0 < K; k0 += 32) {
        float av[16], wv[16];
        if (aok) {
            #pragma unroll
            for (int i = 0; i < 4; i++) {
                float4 t4 = *(const float4*)(Arow + k0 + i * 4);
                av[i*4+0] = t4.x; av[i*4+1] = t4.y; av[i*4+2] = t4.z; av[i*4+3] = t4.w;
            }
        } else {
            #pragma unroll
            for (int i = 0; i < 16; i++) av[i] = 0.f;
        }
        #pragma unroll
        for (int i = 0; i < 4; i++) {
            float4 t4 = *(const float4*)(Wrow + k0 + i * 4);
            wv[i*4+0] = t4.x; wv[i*4+1] = t4.y; wv[i*4+2] = t4.z; wv[i*4+3] = t4.w;
        }
        unsigned au[8], wu[8];
        #pragma unroll
        for (int i = 0; i < 8; i++) {
            au[i] = (unsigned)f2b(av[2*i]) | ((unsigned)f2b(av[2*i+1]) << 16);
            wu[i] = (unsigned)f2b(wv[2*i]) | ((unsigned)f2b(wv[2*i+1]) << 16);
        }
        __syncthreads();
        ((uint4*)asd)[0] = make_uint4(au[0], au[1], au[2], au[3]);
        ((uint4*)(asd + 8))[0] = make_uint4(au[4], au[5], au[6], au[7]);
        ((uint4*)wsd)[0] = make_uint4(wu[0], wu[1], wu[2], wu[3]);
        ((uint4*)(wsd + 8))[0] = make_uint4(wu[4], wu[5], wu[6], wu[7]);
        __syncthreads();

        bf16x8 afr[4], wfr[4];
        #pragma unroll
        for (int mt = 0; mt < 4; mt++)
            afr[mt] = *(const bf16x8*)&As[(wr + mt * 16 + p) * 32 + q * 8];
        #pragma unroll
        for (int nt = 0; nt < 4; nt++)
            wfr[nt] = *(const bf16x8*)&Ws[(wc + nt * 16 + p) * 32 + q * 8];
        #pragma unroll
        for (int mt = 0; mt < 4; mt++)
            #pragma unroll
            for (int nt = 0; nt < 4; nt++)
                acc[mt][nt] = __builtin_amdgcn_mfma_f32_16x16x32_bf16(afr[mt], wfr[nt], acc[mt][nt], 0, 0, 0);
    }

    #pragma unroll
    for (int mt = 0; mt < 4; mt++) {
        #pragma unroll
        for (int r = 0; r < 4; r++) {
            int grow = m0 + wr + mt * 16 + q * 4 + r;
            if (grow >= M) continue;
            #pragma unroll
            for (int nt = 0; nt < 4; nt++) {
                int gcol = n0 + wc + nt * 16 + p;
                float v = acc[mt][nt][r] + bias[gcol];
                if (relu) v = fmaxf(v, 0.f);
                C[(size_t)grow * N + gcol] = v;
            }
        }
    }
}

// ---------------- node QKV GEMM (N=768, K=256): writes Q,K normally, V transposed ----------------
// Vt[z][dh][s] with z = b*2+h.  M = 1024 rows (s*4+b).

__global__ __launch_bounds__(256) void k_gemm_qkv(
    const float* __restrict__ A, const float* __restrict__ W,
    const float* __restrict__ bias, float* __restrict__ C, float* __restrict__ Vt)
{
    __shared__ ushort As[128 * 32];
    __shared__ ushort Ws[128 * 32];
    int tid = threadIdx.x;
    int wave = tid >> 6, lane = tid & 63;
    int wr = (wave >> 1) * 64, wc = (wave & 1) * 64;
    int m0 = blockIdx.y * 128, n0 = blockIdx.x * 128;
    int q = lane >> 4, p = lane & 15;

    f32x4 acc[4][4];
    #pragma unroll
    for (int i = 0; i < 4; i++)
        #pragma unroll
        for (int j = 0; j < 4; j++) acc[i][j] = (f32x4){0.f, 0.f, 0.f, 0.f};

    int srow = tid >> 1;
    int scol = (tid & 1) << 4;
    const float* Arow = A + (size_t)(m0 + srow) * 256 + scol;
    const float* Wrow = W + (size_t)(n0 + srow) * 256 + scol;
    ushort* asd = &As[srow * 32 + scol];
    ushort* wsd = &Ws[srow * 32 + scol];

    for (int k0 = 0; k0 < 256; k0 += 32) {
        float av[16], wv[16];
        #pragma unroll
        for (int i = 0; i < 4; i++) {
            float4 a4 = *(const float4*)(Arow + k0 + i * 4);
            float4 w4 = *(const float4*)(Wrow + k0 + i * 4);
            av[i*4+0] = a4.x; av[i*4+1] = a4.y; av[i*4+2] = a4.z; av[i*4+3] = a4.w;
            wv[i*4+0] = w4.x; wv[i*4+1] = w4.y; wv[i*4+2] = w4.z; wv[i*4+3] = w4.w;
        }
        unsigned au[8], wu[8];
        #pragma unroll
        for (int i = 0; i < 8; i++) {
            au[i] = (unsigned)f2b(av[2*i]) | ((unsigned)f2b(av[2*i+1]) << 16);
            wu[i] = (unsigned)f2b(wv[2*i]) | ((unsigned)f2b(wv[2*i+1]) << 16);
        }
        __syncthreads();
        ((uint4*)asd)[0] = make_uint4(au[0], au[1], au[2], au[3]);
        ((uint4*)(asd + 8))[0] = make_uint4(au[4], au[5], au[6], au[7]);
        ((uint4*)wsd)[0] = make_uint4(wu[0], wu[1], wu[2], wu[3]);
        ((uint4*)(wsd + 8))[0] = make_uint4(wu[4], wu[5], wu[6], wu[7]);
        __syncthreads();

        bf16x8 afr[4], wfr[4];
        #pragma unroll
        for (int mt = 0; mt < 4; mt++)
            afr[mt] = *(const bf16x8*)&As[(wr + mt * 16 + p) * 32 + q * 8];
        #pragma unroll
        for (int nt = 0; nt < 4; nt++)
            wfr[nt] = *(const bf16x8*)&Ws[(wc + nt * 16 + p) * 32 + q * 8];
        #pragma unroll
        for (int mt = 0; mt < 4; mt++)
            #pragma unroll
            for (int nt = 0; nt < 4; nt++)
                acc[mt][nt] = __builtin_amdgcn_mfma_f32_16x16x32_bf16(afr[mt], wfr[nt], acc[mt][nt], 0, 0, 0);
    }

    #pragma unroll
    for (int mt = 0; mt < 4; mt++) {
        #pragma unroll
        for (int r = 0; r < 4; r++) {
            int grow = m0 + wr + mt * 16 + q * 4 + r;
            #pragma unroll
            for (int nt = 0; nt < 4; nt++) {
                int gcol = n0 + wc + nt * 16 + p;
                float v = acc[mt][nt][r] + bias[gcol];
                if (gcol < 512) {
                    C[(size_t)grow * 768 + gcol] = v;
                } else {
                    int hh = (gcol - 512) >> 7, dh = (gcol - 512) & 127;
                    int zz = (grow & 3) * 2 + hh;
                    Vt[(size_t)zz * 32768 + (size_t)dh * 256 + (grow >> 2)] = v;
                }
            }
        }
    }
}

// ---------------- fused QK^T + scale + causal mask + softmax -> bf16 P ----------------
// 64 q-rows x 256 keys per block.  grid (4 qtiles, 8 z).

__global__ __launch_bounds__(256) void k_attn_qks(
    const float* __restrict__ qkv, ushort* __restrict__ P)
{
    __shared__ ushort Qs[64 * 32];
    __shared__ ushort Ks[256 * 32];
    int tid = threadIdx.x;
    int wave = tid >> 6, lane = tid & 63;
    int q = lane >> 4, p = lane & 15;
    int m0 = blockIdx.x * 64;
    int z = blockIdx.y, b = z >> 1, h = z & 1;
    size_t qoff = (size_t)b * 768 + h * 128;

    f32x4 acc[16];
    #pragma unroll
    for (int i = 0; i < 16; i++) acc[i] = (f32x4){0.f, 0.f, 0.f, 0.f};

    int sra = tid >> 2, sca = (tid & 3) << 3;
    const float* Arow = qkv + (size_t)(m0 + sra) * 3072 + qoff + sca;
    const float* Wrow = qkv + (size_t)tid * 3072 + qoff + 256;
    ushort* asd = &Qs[sra * 32 + sca];
    ushort* wsd = &Ks[tid * 32];

    for (int k0 = 0; k0 < 128; k0 += 32) {
        float4 a0 = *(const float4*)(Arow + k0);
        float4 a1 = *(const float4*)(Arow + k0 + 4);
        float av[8] = {a0.x, a0.y, a0.z, a0.w, a1.x, a1.y, a1.z, a1.w};
        float wv[32];
        #pragma unroll
        for (int i = 0; i < 8; i++) {
            float4 w4 = *(const float4*)(Wrow + k0 + i * 4);
            wv[i*4+0] = w4.x; wv[i*4+1] = w4.y; wv[i*4+2] = w4.z; wv[i*4+3] = w4.w;
        }
        unsigned au[4], wu[16];
        #pragma unroll
        for (int i = 0; i < 4; i++) au[i] = (unsigned)f2b(av[2*i]) | ((unsigned)f2b(av[2*i+1]) << 16);
        #pragma unroll
        for (int i = 0; i < 16; i++) wu[i] = (unsigned)f2b(wv[2*i]) | ((unsigned)f2b(wv[2*i+1]) << 16);
        __syncthreads();
        ((uint4*)asd)[0] = make_uint4(au[0], au[1], au[2], au[3]);
        ((uint4*)wsd)[0] = make_uint4(wu[0], wu[1], wu[2], wu[3]);
        ((uint4*)(wsd + 8))[0] = make_uint4(wu[4], wu[5], wu[6], wu[7]);
        ((uint4*)(wsd + 16))[0] = make_uint4(wu[8], wu[9], wu[10], wu[11]);
        ((uint4*)(wsd + 24))[0] = make_uint4(wu[12], wu[13], wu[14], wu[15]);
        __syncthreads();

        bf16x8 af = *(const bf16x8*)&Qs[(wave * 16 + p) * 32 + q * 8];
        #pragma unroll
        for (int nt = 0; nt < 16; nt++) {
            bf16x8 bf = *(const bf16x8*)&Ks[(nt * 16 + p) * 32 + q * 8];
            acc[nt] = __builtin_amdgcn_mfma_f32_16x16x32_bf16(af, bf, acc[nt], 0, 0, 0);
        }
    }

    ushort* Pz = P + (size_t)z * 65536;
    #pragma unroll
    for (int reg = 0; reg < 4; reg++) {
        int row = m0 + wave * 16 + q * 4 + reg;   // global query index
        float v[16]; float mx = -1e30f;
        #pragma unroll
        for (int nt = 0; nt < 16; nt++) {
            int col = nt * 16 + p;
            float val = (col <= row) ? acc[nt][reg] * SCALE : -1e30f;
            v[nt] = val; mx = fmaxf(mx, val);
        }
        mx = fmaxf(mx, __shfl_xor(mx, 1)); mx = fmaxf(mx, __shfl_xor(mx, 2));
        mx = fmaxf(mx, __shfl_xor(mx, 4)); mx = fmaxf(mx, __shfl_xor(mx, 8));
        float s = 0.f;
        #pragma unroll
        for (int nt = 0; nt < 16; nt++) {
            int col = nt * 16 + p;
            float e = (col <= row) ? __expf(v[nt] - mx) : 0.f;
            v[nt] = e; s += e;
        }
        s += __shfl_xor(s, 1); s += __shfl_xor(s, 2); s += __shfl_xor(s, 4); s += __shfl_xor(s, 8);
        float inv = 1.f / s;
        #pragma unroll
        for (int nt = 0; nt < 16; nt++)
            Pz[(size_t)row * 256 + nt * 16 + p] = f2b(v[nt] * inv);
    }
}

// ---------------- PV: O = P @ V, P bf16 [256q][256k], Vt [128dh][256k] ----------------
// 64 q x 128 dh per block, grid (4 qtiles, 8 z). Writes node activation layout.

__global__ __launch_bounds__(256) void k_attn_pvt(
    const ushort* __restrict__ P, const float* __restrict__ Vt,
    float* __restrict__ out)
{
    __shared__ ushort As[64 * 32];
    __shared__ ushort Bs[128 * 32];
    int tid = threadIdx.x;
    int wave = tid >> 6, lane = tid & 63;
    int q = lane >> 4, p = lane & 15;
    int m0 = blockIdx.x * 64;
    int z = blockIdx.y, b = z >> 1, h = z & 1;

    f32x4 acc[8];
    #pragma unroll
    for (int i = 0; i < 8; i++) acc[i] = (f32x4){0.f, 0.f, 0.f, 0.f};

    int sra = tid >> 2, sca = (tid & 3) << 3;
    const ushort* Prow = P + (size_t)z * 65536 + (size_t)(m0 + sra) * 256 + sca;
    int srb = tid >> 1, scb = (tid & 1) << 4;
    const float* Vrow = Vt + (size_t)z * 32768 + (size_t)srb * 256 + scb;
    ushort* asd = &As[sra * 32 + sca];
    ushort* wsd = &Bs[srb * 32 + scb];

    for (int k0 = 0; k0 < 256; k0 += 32) {
        uint4 pa = *(const uint4*)(Prow + k0);
        float wv[16];
        #pragma unroll
        for (int i = 0; i < 4; i++) {
            float4 w4 = *(const float4*)(Vrow + k0 + i * 4);
            wv[i*4+0] = w4.x; wv[i*4+1] = w4.y; wv[i*4+2] = w4.z; wv[i*4+3] = w4.w;
        }
        unsigned wu[8];
        #pragma unroll
        for (int i = 0; i < 8; i++) wu[i] = (unsigned)f2b(wv[2*i]) | ((unsigned)f2b(wv[2*i+1]) << 16);
        __syncthreads();
        ((uint4*)asd)[0] = pa;
        ((uint4*)wsd)[0] = make_uint4(wu[0], wu[1], wu[2], wu[3]);
        ((uint4*)(wsd + 8))[0] = make_uint4(wu[4], wu[5], wu[6], wu[7]);
        __syncthreads();

        bf16x8 af = *(const bf16x8*)&As[(wave * 16 + p) * 32 + q * 8];
        #pragma unroll
        for (int nt = 0; nt < 8; nt++) {
            bf16x8 bf = *(const bf16x8*)&Bs[(nt * 16 + p) * 32 + q * 8];
            acc[nt] = __builtin_amdgcn_mfma_f32_16x16x32_bf16(af, bf, acc[nt], 0, 0, 0);
        }
    }

    #pragma unroll
    for (int reg = 0; reg < 4; reg++) {
        int s = m0 + wave * 16 + q * 4 + reg;
        #pragma unroll
        for (int nt = 0; nt < 8; nt++) {
            int dh = nt * 16 + p;
            out[(size_t)s * 1024 + (size_t)b * 256 + h * 128 + dh] = acc[nt][reg];
        }
    }
}

// ---------------- fused GEMM (N=256,K=256) + residual + LayerNorm (+optional 2nd LN) ----------------
// C = LN2?(LN1(res + A@W^T + bias))   64 rows per block.

__global__ __launch_bounds__(256) void k_gemm_ln(
    const float* __restrict__ A, const float* __restrict__ W,
    const float* __restrict__ bias, const float* __restrict__ res,
    const float* __restrict__ g1, const float* __restrict__ b1,
    const float* __restrict__ g2, const float* __restrict__ b2,
    float* __restrict__ C, int M, int dln)
{
    __shared__ ushort As[64 * 32];
    __shared__ ushort Ws[256 * 32];
    int tid = threadIdx.x;
    int wave = tid >> 6, lane = tid & 63;
    int q = lane >> 4, p = lane & 15;
    int m0 = blockIdx.x * 64;

    f32x4 acc[16];
    #pragma unroll
    for (int i = 0; i < 16; i++) acc[i] = (f32x4){0.f, 0.f, 0.f, 0.f};

    int sra = tid >> 2, sca = (tid & 3) << 3;
    const float* Arow = A + (size_t)(m0 + sra) * 256 + sca;
    bool aok = (m0 + sra) < M;
    const float* Wrow = W + (size_t)tid * 256;
    ushort* asd = &As[sra * 32 + sca];
    ushort* wsd = &Ws[tid * 32];

    for (int k0 = 0; k0 < 256; k0 += 32) {
        float av[8];
        if (aok) {
            float4 a0 = *(const float4*)(Arow + k0);
            float4 a1 = *(const float4*)(Arow + k0 + 4);
            av[0]=a0.x; av[1]=a0.y; av[2]=a0.z; av[3]=a0.w;
            av[4]=a1.x; av[5]=a1.y; av[6]=a1.z; av[7]=a1.w;
        } else {
            #pragma unroll
            for (int i = 0; i < 8; i++) av[i] = 0.f;
        }
        float wv[32];
        #pragma unroll
        for (int i = 0; i < 8; i++) {
            float4 w4 = *(const float4*)(Wrow + k0 + i * 4);
            wv[i*4+0] = w4.x; wv[i*4+1] = w4.y; wv[i*4+2] = w4.z; wv[i*4+3] = w4.w;
        }
        unsigned au[4], wu[16];
        #pragma unroll
        for (int i = 0; i < 4; i++) au[i] = (unsigned)f2b(av[2*i]) | ((unsigned)f2b(av[2*i+1]) << 16);
        #pragma unroll
        for (int i = 0; i < 16; i++) wu[i] = (unsigned)f2b(wv[2*i]) | ((unsigned)f2b(wv[2*i+1]) << 16);
        __syncthreads();
        ((uint4*)asd)[0] = make_uint4(au[0], au[1], au[2], au[3]);
        ((uint4*)wsd)[0] = make_uint4(wu[0], wu[1], wu[2], wu[3]);
        ((uint4*)(wsd + 8))[0] = make_uint4(wu[4], wu[5], wu[6], wu[7]);
        ((uint4*)(wsd + 16))[0] = make_uint4(wu[8], wu[9], wu[10], wu[11]);
        ((uint4*)(wsd + 24))[0] = make_uint4(wu[12], wu[13], wu[14], wu[15]);
        __syncthreads();

        bf16x8 af = *(const bf16x8*)&As[(wave * 16 + p) * 32 + q * 8];
        #pragma unroll
        for (int nt = 0; nt < 16; nt++) {
            bf16x8 bf = *(const bf16x8*)&Ws[(nt * 16 + p) * 32 + q * 8];
            acc[nt] = __builtin_amdgcn_mfma_f32_16x16x32_bf16(af, bf, acc[nt], 0, 0, 0);
        }
    }

    #pragma unroll
    for (int reg = 0; reg < 4; reg++) {
        int row = m0 + wave * 16 + q * 4 + reg;
        bool ok = row < M;
        float v[16]; float s = 0.f;
        #pragma unroll
        for (int nt = 0; nt < 16; nt++) {
            int col = nt * 16 + p;
            float t = ok ? (acc[nt][reg] + bias[col] + res[(size_t)row * 256 + col]) : 0.f;
            v[nt] = t; s += t;
        }
        s += __shfl_xor(s, 1); s += __shfl_xor(s, 2); s += __shfl_xor(s, 4); s += __shfl_xor(s, 8);
        float mean = s * (1.f / 256.f);
        float qv = 0.f;
        #pragma unroll
        for (int nt = 0; nt < 16; nt++) { float d = v[nt] - mean; qv += d * d; }
        qv += __shfl_xor(qv, 1); qv += __shfl_xor(qv, 2); qv += __shfl_xor(qv, 4); qv += __shfl_xor(qv, 8);
        float rstd = rsqrtf(qv * (1.f / 256.f) + 1e-5f);
        #pragma unroll
        for (int nt = 0; nt < 16; nt++) {
            int col = nt * 16 + p;
            v[nt] = (v[nt] - mean) * rstd * g1[col] + b1[col];
        }
        if (dln) {
            float s2 = 0.f;
            #pragma unroll
            for (int nt = 0; nt < 16; nt++) s2 += v[nt];
            s2 += __shfl_xor(s2, 1); s2 += __shfl_xor(s2, 2); s2 += __shfl_xor(s2, 4); s2 += __shfl_xor(s2, 8);
            float m2 = s2 * (1.f / 256.f);
            float q2 = 0.f;
            #pragma unroll
            for (int nt = 0; nt < 16; nt++) { float d = v[nt] - m2; q2 += d * d; }
            q2 += __shfl_xor(q2, 1); q2 += __shfl_xor(q2, 2); q2 += __shfl_xor(q2, 4); q2 += __shfl_xor(q2, 8);
            float rs2 = rsqrtf(q2 * (1.f / 256.f) + 1e-5f);
            #pragma unroll
            for (int nt = 0; nt < 16; nt++) {
                int col = nt * 16 + p;
                v[nt] = (v[nt] - m2) * rs2 * g2[col] + b2[col];
            }
        }
        if (ok) {
            #pragma unroll
            for (int nt = 0; nt < 16; nt++)
                C[(size_t)row * 256 + nt * 16 + p] = v[nt];
        }
    }
}

// ---------------- generic fp32 GEMM (input projection K=54 only) ----------------

__global__ __launch_bounds__(256) void k_gemm(
    const float* __restrict__ A, const float* __restrict__ W,
    const float* __restrict__ bias, float* __restrict__ C,
    int M, int N, int K, int relu)
{
    __shared__ __align__(16) float As[16][68];
    __shared__ __align__(16) float Ws[16][68];
    int tx = threadIdx.x, ty = threadIdx.y;
    int tid = ty * 16 + tx;
    int m0 = blockIdx.y * 64, n0 = blockIdx.x * 64;
    float acc[4][4] = {{0.f}};
    int r  = tid >> 2;
    int kk = (tid & 3) << 2;
    bool k4 = ((K & 3) == 0);
    for (int k0 = 0; k0 < K; k0 += 16) {
        float4 av = make_float4(0.f, 0.f, 0.f, 0.f);
        float4 wv = make_float4(0.f, 0.f, 0.f, 0.f);
        int gm = m0 + r, gk = k0 + kk;
        if (gm < M) {
            if (k4 && gk + 4 <= K) av = *(const float4*)(A + (size_t)gm * K + gk);
            else {
                float tv[4];
                for (int i = 0; i < 4; i++) tv[i] = (gk + i < K) ? A[(size_t)gm * K + gk + i] : 0.f;
                av = make_float4(tv[0], tv[1], tv[2], tv[3]);
            }
        }
        int gn = n0 + r;
        if (gn < N) {
            if (k4 && gk + 4 <= K) wv = *(const float4*)(W + (size_t)gn * K + gk);
            else {
                float tv[4];
                for (int i = 0; i < 4; i++) tv[i] = (gk + i < K) ? W[(size_t)gn * K + gk + i] : 0.f;
                wv = make_float4(tv[0], tv[1], tv[2], tv[3]);
            }
        }
        As[kk + 0][r] = av.x; As[kk + 1][r] = av.y; As[kk + 2][r] = av.z; As[kk + 3][r] = av.w;
        Ws[kk + 0][r] = wv.x; Ws[kk + 1][r] = wv.y; Ws[kk + 2][r] = wv.z; Ws[kk + 3][r] = wv.w;
        __syncthreads();
        #pragma unroll
        for (int k = 0; k < 16; k++) {
            float4 a4 = *(const float4*)&As[k][ty << 2];
            float4 b4 = *(const float4*)&Ws[k][tx << 2];
            float a[4] = {a4.x, a4.y, a4.z, a4.w};
            float b[4] = {b4.x, b4.y, b4.z, b4.w};
            #pragma unroll
            for (int i = 0; i < 4; i++)
                #pragma unroll
                for (int j = 0; j < 4; j++)
                    acc[i][j] = fmaf(a[i], b[j], acc[i][j]);
        }
        __syncthreads();
    }
    #pragma unroll
    for (int i = 0; i < 4; i++) {
        int gm = m0 + (ty << 2) + i;
        if (gm >= M) continue;
        #pragma unroll
        for (int j = 0; j < 4; j++) {
            int gn = n0 + (tx << 2) + j;
            if (gn >= N) continue;
            float v = acc[i][j] + bias[gn];
            if (relu) v = fmaxf(v, 0.f);
            C[(size_t)gm * N + gn] = v;
        }
    }
}

// ---------------- residual + LayerNorm (mode 1: broadcast delta) ----------------

__global__ __launch_bounds__(256) void k_add_ln(
    const float* __restrict__ x, const float* __restrict__ delta,
    const float* __restrict__ g, const float* __restrict__ bta,
    float* __restrict__ out, int M, int mode)
{
    int row = blockIdx.x * 4 + (threadIdx.x >> 6);
    int t = threadIdx.x & 63;
    if (row >= M) return;
    float4 v = ((const float4*)(x + (size_t)row * HH))[t];
    if (mode == 0) {
        float4 d = ((const float4*)(delta + (size_t)row * HH))[t];
        v.x += d.x; v.y += d.y; v.z += d.z; v.w += d.w;
    } else if (mode == 1) {
        float4 d = ((const float4*)(delta + (size_t)(row & 3) * HH))[t];
        v.x += d.x; v.y += d.y; v.z += d.z; v.w += d.w;
    }
    float s = v.x + v.y + v.z + v.w;
    for (int o = 32; o; o >>= 1) s += __shfl_down(s, o);
    float mean = __shfl(s, 0) * (1.f / 256.f);
    float cx = v.x - mean, cy = v.y - mean, cz = v.z - mean, cw = v.w - mean;
    float q = cx * cx + cy * cy + cz * cz + cw * cw;
    for (int o = 32; o; o >>= 1) q += __shfl_down(q, o);
    float rstd = rsqrtf(__shfl(q, 0) * (1.f / 256.f) + 1e-5f);
    float4 gg = ((const float4*)g)[t];
    float4 bb = ((const float4*)bta)[t];
    float4 o4;
    o4.x = cx * rstd * gg.x + bb.x;
    o4.y = cy * rstd * gg.y + bb.y;
    o4.z = cz * rstd * gg.z + bb.z;
    o4.w = cw * rstd * gg.w + bb.w;
    ((float4*)(out + (size_t)row * HH))[t] = o4;
}

// ---------------- BatchNorm partial sums ----------------

__global__ __launch_bounds__(256) void k_bn_part(const float* __restrict__ x, float* __restrict__ sums) {
    int t = threadIdx.x;
    int r0 = blockIdx.x * 16;
    float s = 0.f, s2 = 0.f;
    for (int r = r0; r < r0 + 16; r++) {
        float v = x[(size_t)r * 256 + t];
        s += v; s2 += v * v;
    }
    atomicAdd(&sums[t], s);
    atomicAdd(&sums[256 + t], s2);
}

// ---------------- BN-finalize + SELU + positional encoding ----------------

__global__ __launch_bounds__(256) void k_bn_selu_pe(
    const float* __restrict__ x0, const float* __restrict__ sums,
    const float* __restrict__ g, const float* __restrict__ b,
    const int* __restrict__ atom_i, float* __restrict__ out)
{
    int row = blockIdx.x, t = threadIdx.x;
    float m = sums[t] * (1.f / 1024.f);
    float var = sums[256 + t] * (1.f / 1024.f) - m * m;
    float rstd = rsqrtf(var + 1e-5f);
    float v = x0[(size_t)row * 256 + t];
    v = (v - m) * rstd * g[t] + b[t];
    const float SC = 1.0507009873554805f, AL = 1.6732632423543772f;
    v = SC * (v > 0.f ? v : AL * expm1f(v));
    float pos = (float)atom_i[row];
    float freq = expf(-(float)t * (9.210340371976184f / 256.f));
    float ang = pos * freq;
    float pe = (t & 1) ? cosf(ang) : sinf(ang);
    out[(size_t)row * 256 + t] = v + pe;
}

// ---------------- both-layer node cross-attn constant: crO[l][b][256] ----------------

__global__ __launch_bounds__(256) void k_cross2(
    const float* __restrict__ z, const float* __restrict__ cqkv_w, const float* __restrict__ cqkv_b,
    const float* __restrict__ co_w, const float* __restrict__ co_b, float* __restrict__ crO)
{
    int m = blockIdx.x, l = blockIdx.y;
    int t = threadIdx.x;
    __shared__ float zs[256], ct[256];
    zs[t] = z[m * 256 + t];
    __syncthreads();
    const float* wv = cqkv_w + (size_t)l * 768 * 256 + 512 * 256 + (size_t)t * 256;
    float a = cqkv_b[l * 768 + 512 + t];
    for (int d = 0; d < 256; d += 4) {
        float4 w4 = *(const float4*)(wv + d);
        a += zs[d] * w4.x + zs[d+1] * w4.y + zs[d+2] * w4.z + zs[d+3] * w4.w;
    }
    ct[t] = a;
    __syncthreads();
    const float* ow = co_w + (size_t)l * 65536 + (size_t)t * 256;
    float o = co_b[l * 256 + t];
    for (int d = 0; d < 256; d += 4) {
        float4 w4 = *(const float4*)(ow + d);
        o += ct[d] * w4.x + ct[d+1] * w4.y + ct[d+2] * w4.z + ct[d+3] * w4.w;
    }
    crO[l * 1024 + m * 256 + t] = o;
}

// ---------------- edge group self-attention ----------------

__global__ __launch_bounds__(256) void k_edge_self_attn(
    const float* __restrict__ qkv, float* __restrict__ out)
{
    int g = blockIdx.x + 1;
    int b = blockIdx.y;
    int gs = min(g, 12);
    int base = (g <= 13) ? g * (g - 1) / 2 : 78 + (g - 13) * 12;
    int h = threadIdx.x >> 7;
    int t = threadIdx.x & 127;
    __shared__ float qs[2][12][128], ks[2][12][128], vs[2][12][128];
    __shared__ float ps[2][12][12];
    for (int i = 0; i < gs; i++) {
        size_t row = ((size_t)(base + i) * BB + b) * 768 + h * 128 + t;
        qs[h][i][t] = qkv[row];
        ks[h][i][t] = qkv[row + 256];
        vs[h][i][t] = qkv[row + 512];
    }
    __syncthreads();
    for (int p = t; p < gs * gs; p += 128) {
        int i = p / gs, j = p - i * gs;
        float acc = 0.f;
        for (int d = 0; d < 128; d++) acc = fmaf(qs[h][i][d], ks[h][j][d], acc);
        ps[h][i][j] = acc * SCALE;
    }
    __syncthreads();
    if (t < gs) {
        float m = -1e30f;
        for (int j = 0; j < gs; j++) m = fmaxf(m, ps[h][t][j]);
        float e[12]; float s = 0.f;
        for (int j = 0; j < gs; j++) { e[j] = expf(ps[h][t][j] - m); s += e[j]; }
        float inv = 1.f / s;
        for (int j = 0; j < gs; j++) ps[h][t][j] = e[j] * inv;
    }
    __syncthreads();
    for (int i = 0; i < gs; i++) {
        float acc = 0.f;
        for (int j = 0; j < gs; j++) acc = fmaf(ps[h][i][j], vs[h][j][t], acc);
        out[((size_t)(base + i) * BB + b) * 256 + h * 128 + t] = acc;
    }
}

// ---------------- edge 2-key cross-attention ----------------

__global__ __launch_bounds__(128) void k_edge_cross_attn(
    const float* __restrict__ Q, const float* __restrict__ KV,
    const int* __restrict__ grp, float* __restrict__ out)
{
    int e = blockIdx.x, b = blockIdx.y;
    int h = threadIdx.x >> 6, l = threadIdx.x & 63;
    int g = grp[e];
    size_t qrow = ((size_t)e * BB + b) * 256 + h * 128;
    float qa = Q[qrow + l], qb = Q[qrow + 64 + l];
    size_t k0r = (size_t)b * 512 + h * 128;
    size_t k1r = ((size_t)(g + 1) * BB + b) * 512 + h * 128;
    float p0 = qa * KV[k0r + l] + qb * KV[k0r + 64 + l];
    float p1 = qa * KV[k1r + l] + qb * KV[k1r + 64 + l];
    for (int o = 32; o; o >>= 1) { p0 += __shfl_down(p0, o); p1 += __shfl_down(p1, o); }
    p0 = __shfl(p0, 0) * SCALE;
    p1 = __shfl(p1, 0) * SCALE;
    float m = fmaxf(p0, p1);
    float e0 = expf(p0 - m), e1 = expf(p1 - m);
    float inv = 1.f / (e0 + e1);
    e0 *= inv; e1 *= inv;
    out[qrow + l]      = e0 * KV[k0r + 256 + l]      + e1 * KV[k1r + 256 + l];
    out[qrow + 64 + l] = e0 * KV[k0r + 256 + 64 + l] + e1 * KV[k1r + 256 + 64 + l];
}

// ---------------- gather + build_mem fused ----------------

__global__ __launch_bounds__(256) void k_gather_mem(
    const float* __restrict__ z, const float* __restrict__ nemb,
    const int* __restrict__ idxt, float* __restrict__ etgt, float* __restrict__ memb)
{
    int r = blockIdx.x, t = threadIdx.x;
    if (r < LEB) {
        int e = r >> 2, b = r & 3;
        etgt[(size_t)r * 256 + t] = nemb[((size_t)idxt[e] * 4 + b) * 256 + t];
    } else {
        int rm = r - LEB;
        int m = rm >> 2, b = rm & 3;
        memb[(size_t)rm * 256 + t] = (m == 0) ? z[(size_t)b * 256 + t]
                                              : nemb[((size_t)(m - 1) * 4 + b) * 256 + t];
    }
}

// ---------------- fused cross-entropy ----------------

__global__ __launch_bounds__(256) void k_ce_node(
    const float* __restrict__ emb,
    const float* __restrict__ w0, const float* __restrict__ b0,
    const float* __restrict__ w1, const float* __restrict__ b1,
    const float* __restrict__ w2, const float* __restrict__ b2,
    const int* __restrict__ y, int M, float invM, float* __restrict__ lossOut)
{
    int wave = threadIdx.x >> 6, lane = threadIdx.x & 63;
    int wid = blockIdx.x * 4 + wave;
    float local = 0.f;
    for (int r = wid; r < M; r += gridDim.x * 4) {
        float4 x = ((const float4*)(emb + (size_t)r * 256))[lane];
        float acc[54];
        #pragma unroll
        for (int c = 0; c < 40; c++) {
            float4 wv = ((const float4*)(w0 + (size_t)c * 256))[lane];
            acc[c] = x.x * wv.x + x.y * wv.y + x.z * wv.z + x.w * wv.w;
        }
        #pragma unroll
        for (int c = 0; c < 8; c++) {
            float4 wv = ((const float4*)(w1 + (size_t)c * 256))[lane];
            acc[40 + c] = x.x * wv.x + x.y * wv.y + x.z * wv.z + x.w * wv.w;
        }
        #pragma unroll
        for (int c = 0; c < 6; c++) {
            float4 wv = ((const float4*)(w2 + (size_t)c * 256))[lane];
            acc[48 + c] = x.x * wv.x + x.y * wv.y + x.z * wv.z + x.w * wv.w;
        }
        #pragma unroll
        for (int c = 0; c < 54; c++)
            for (int o = 32; o; o >>= 1) acc[c] += __shfl_down(acc[c], o);
        if (lane == 0) {
            int y0 = y[(size_t)r * 3 + 0], y1 = y[(size_t)r * 3 + 1], y2 = y[(size_t)r * 3 + 2];
            float m0 = -1e30f, m1 = -1e30f, m2 = -1e30f;
            float lg[54];
            for (int c = 0; c < 40; c++) { lg[c] = acc[c] + b0[c]; m0 = fmaxf(m0, lg[c]); }
            for (int c = 0; c < 8; c++)  { lg[40 + c] = acc[40 + c] + b1[c]; m1 = fmaxf(m1, lg[40 + c]); }
            for (int c = 0; c < 6; c++)  { lg[48 + c] = acc[48 + c] + b2[c]; m2 = fmaxf(m2, lg[48 + c]); }
            float s0 = 0.f, s1 = 0.f, s2 = 0.f;
            for (int c = 0; c < 40; c++) s0 += expf(lg[c] - m0);
            for (int c = 0; c < 8; c++)  s1 += expf(lg[40 + c] - m1);
            for (int c = 0; c < 6; c++)  s2 += expf(lg[48 + c] - m2);
            local += (m0 + logf(s0) - lg[y0]) + (m1 + logf(s1) - lg[40 + y1]) + (m2 + logf(s2) - lg[48 + y2]);
        }
    }
    __shared__ float ls[4];
    if (lane == 0) ls[wave] = local;
    __syncthreads();
    if (threadIdx.x == 0)
        atomicAdd(lossOut, (ls[0] + ls[1] + ls[2] + ls[3]) * invM);
}

__global__ __launch_bounds__(256) void k_ce_edge(
    const float* __restrict__ emb,
    const float* __restrict__ w0, const float* __restrict__ b0,
    const float* __restrict__ w1, const float* __restrict__ b1,
    const int* __restrict__ y, int M, float invM, float* __restrict__ lossOut)
{
    int wave = threadIdx.x >> 6, lane = threadIdx.x & 63;
    int wid = blockIdx.x * 4 + wave;
    float local = 0.f;
    for (int r = wid; r < M; r += gridDim.x * 4) {
        float4 x = ((const float4*)(emb + (size_t)r * 256))[lane];
        float acc[9];
        #pragma unroll
        for (int c = 0; c < 5; c++) {
            float4 wv = ((const float4*)(w0 + (size_t)c * 256))[lane];
            acc[c] = x.x * wv.x + x.y * wv.y + x.z * wv.z + x.w * wv.w;
        }
        #pragma unroll
        for (int c = 0; c < 4; c++) {
            float4 wv = ((const float4*)(w1 + (size_t)c * 256))[lane];
            acc[5 + c] = x.x * wv.x + x.y * wv.y + x.z * wv.z + x.w * wv.w;
        }
        #pragma unroll
        for (int c = 0; c < 9; c++)
            for (int o = 32; o; o >>= 1) acc[c] += __shfl_down(acc[c], o);
        if (lane == 0) {
            int y0 = y[(size_t)r * 2 + 0], y1 = y[(size_t)r * 2 + 1];
            float lg[9];
            float m0 = -1e30f, m1 = -1e30f;
            for (int c = 0; c < 5; c++) { lg[c] = acc[c] + b0[c]; m0 = fmaxf(m0, lg[c]); }
            for (int c = 0; c < 4; c++) { lg[5 + c] = acc[5 + c] + b1[c]; m1 = fmaxf(m1, lg[5 + c]); }
            float s0 = 0.f, s1 = 0.f;
            for (int c = 0; c < 5; c++) s0 += expf(lg[c] - m0);
            for (int c = 0; c < 4; c++) s1 += expf(lg[5 + c] - m1);
            local += (m0 + logf(s0) - lg[y0]) + (m1 + logf(s1) - lg[5 + y1]);
        }
    }
    __shared__ float ls[4];
    if (lane == 0) ls[wave] = local;
    __syncthreads();
    if (threadIdx.x == 0)
        atomicAdd(lossOut, (ls[0] + ls[1] + ls[2] + ls[3]) * invM);
}

// ---------------- host ----------------

extern "C" void kernel_launch(void* const* d_in, const int* in_sizes, int n_in,
                              void* d_out, int out_size, void* d_ws, size_t ws_size,
                              hipStream_t stream)
{
    (void)in_sizes; (void)n_in; (void)out_size; (void)ws_size;
    const float* zin      = (const float*)d_in[0];
    const int*   atom_i   = (const int*)d_in[1];
    const float* atom_x   = (const float*)d_in[2];
    const int*   atom_y   = (const int*)d_in[3];
    const int*   bond_y   = (const int*)d_in[4];
    const float* Wp       = (const float*)d_in[5];
    const float* bp       = (const float*)d_in[6];
    const float* bn_g     = (const float*)d_in[7];
    const float* bn_b     = (const float*)d_in[8];
    const float* nd_qkv_w = (const float*)d_in[9];
    const float* nd_qkv_b = (const float*)d_in[10];
    const float* nd_so_w  = (const float*)d_in[11];
    const float* nd_so_b  = (const float*)d_in[12];
    const float* nd_cqkv_w= (const float*)d_in[13];
    const float* nd_cqkv_b= (const float*)d_in[14];
    const float* nd_co_w  = (const float*)d_in[15];
    const float* nd_co_b  = (const float*)d_in[16];
    const float* nd_ff1_w = (const float*)d_in[17];
    const float* nd_ff1_b = (const float*)d_in[18];
    const float* nd_ff2_w = (const float*)d_in[19];
    const float* nd_ff2_b = (const float*)d_in[20];
    const float* nd_ln_g  = (const float*)d_in[21];
    const float* nd_ln_b  = (const float*)d_in[22];
    const float* nd_fn_g  = (const float*)d_in[23];
    const float* nd_fn_b  = (const float*)d_in[24];
    const float* ed_qkv_w = (const float*)d_in[25];
    const float* ed_qkv_b = (const float*)d_in[26];
    const float* ed_so_w  = (const float*)d_in[27];
    const float* ed_so_b  = (const float*)d_in[28];
    const float* ed_cqkv_w= (const float*)d_in[29];
    const float* ed_cqkv_b= (const float*)d_in[30];
    const float* ed_co_w  = (const float*)d_in[31];
    const float* ed_co_b  = (const float*)d_in[32];
    const float* ed_ff1_w = (const float*)d_in[33];
    const float* ed_ff1_b = (const float*)d_in[34];
    const float* ed_ff2_w = (const float*)d_in[35];
    const float* ed_ff2_b = (const float*)d_in[36];
    const float* ed_ln_g  = (const float*)d_in[37];
    const float* ed_ln_b  = (const float*)d_in[38];
    const float* ed_fn_g  = (const float*)d_in[39];
    const float* ed_fn_b  = (const float*)d_in[40];
    const float* nc0_w = (const float*)d_in[41]; const float* nc0_b = (const float*)d_in[42];
    const float* nc1_w = (const float*)d_in[43]; const float* nc1_b = (const float*)d_in[44];
    const float* nc2_w = (const float*)d_in[45]; const float* nc2_b = (const float*)d_in[46];
    const float* ec0_w = (const float*)d_in[47]; const float* ec0_b = (const float*)d_in[48];
    const float* ec1_w = (const float*)d_in[49]; const float* ec1_b = (const float*)d_in[50];

    float* out = (float*)d_out;

    char* wsb = (char*)d_ws;
    size_t off = 0;
    auto alloc = [&](size_t nbytes) -> void* {
        void* p = (void*)(wsb + off);
        off += (nbytes + 255) / 256 * 256;
        return p;
    };
    float* x0    = (float*)alloc(1024 * 256 * 4);
    float* tgt   = (float*)alloc(1024 * 256 * 4);
    float* nqkv  = (float*)alloc(1024 * 768 * 4);
    float* t1    = (float*)alloc(1024 * 256 * 4);
    float* nemb  = (float*)alloc(1024 * 256 * 4);
    float* bnsums= (float*)alloc(512 * 4);
    float* crO   = (float*)alloc(2 * 1024 * 4);
    float* memb  = (float*)alloc(1028 * 256 * 4);
    float* KV    = (float*)alloc(1028 * 512 * 4);
    ushort* Sb   = (ushort*)alloc(8 * 65536 * 2);
    float* Vt    = (float*)alloc(8 * 32768 * 4);
    float* etgt  = (float*)alloc((size_t)LEB * 256 * 4);
    float* eqkv  = (float*)alloc((size_t)LEB * 768 * 4);
    float* et1   = (float*)alloc((size_t)LEB * 256 * 4);
    int* grp   = (int*)alloc(LE * 4);
    int* idxt  = (int*)alloc(LE * 4);

    k_init<<<13, 256, 0, stream>>>(out, bnsums, grp, idxt);

    // node input: projection + BN(training stats) + SELU + positional encoding
    k_gemm<<<dim3(4, 16), dim3(16, 16), 0, stream>>>(atom_x, Wp, bp, x0, 1024, 256, 54, 0);
    k_bn_part<<<64, 256, 0, stream>>>(x0, bnsums);
    k_bn_selu_pe<<<1024, 256, 0, stream>>>(x0, bnsums, bn_g, bn_b, atom_i, tgt);

    // both layers' cross-attn constant (depends only on z)
    k_cross2<<<dim3(4, 2), 256, 0, stream>>>(zin, nd_cqkv_w, nd_cqkv_b, nd_co_w, nd_co_b, crO);

    // node decoder: 2 layers
    for (int l = 0; l < 2; l++) {
        k_gemm_qkv<<<dim3(6, 8), 256, 0, stream>>>(tgt, nd_qkv_w + (size_t)l * 768 * 256,
                                                   nd_qkv_b + l * 768, nqkv, Vt);
        k_attn_qks<<<dim3(4, 8), 256, 0, stream>>>(nqkv, Sb);
        k_attn_pvt<<<dim3(4, 8), 256, 0, stream>>>(Sb, Vt, t1);
        k_gemm_ln<<<16, 256, 0, stream>>>(t1, nd_so_w + (size_t)l * 65536, nd_so_b + l * 256,
                                          tgt, nd_ln_g + (l * 3 + 0) * 256, nd_ln_b + (l * 3 + 0) * 256,
                                          nullptr, nullptr, tgt, 1024, 0);
        k_add_ln<<<256, 256, 0, stream>>>(tgt, crO + l * 1024,
                                          nd_ln_g + (l * 3 + 1) * 256, nd_ln_b + (l * 3 + 1) * 256,
                                          tgt, 1024, 1);
        k_gemm_mfma<<<dim3(2, 8), 256, 0, stream>>>(tgt, nd_ff1_w + (size_t)l * 65536,
                                                    nd_ff1_b + l * 256, t1, 1024, 256, 256, 1);
        if (l == 0) {
            k_gemm_ln<<<16, 256, 0, stream>>>(t1, nd_ff2_w, nd_ff2_b, tgt,
                                              nd_ln_g + 2 * 256, nd_ln_b + 2 * 256,
                                              nullptr, nullptr, tgt, 1024, 0);
        } else {
            k_gemm_ln<<<16, 256, 0, stream>>>(t1, nd_ff2_w + 65536, nd_ff2_b + 256, tgt,
                                              nd_ln_g + 5 * 256, nd_ln_b + 5 * 256,
                                              nd_fn_g, nd_fn_b, nemb, 1024, 1);
        }
    }

    // node losses
    k_ce_node<<<128, 256, 0, stream>>>(nemb, nc0_w, nc0_b, nc1_w, nc1_b, nc2_w, nc2_b,
                                       atom_y, 1024, 1.f / 1024.f, out);

    // edge path
    k_gather_mem<<<LEB + 1028, 256, 0, stream>>>(zin, nemb, idxt, etgt, memb);
    k_gemm_mfma<<<dim3(4, 9), 256, 0, stream>>>(memb, ed_cqkv_w + 256 * 256, ed_cqkv_b + 256,
                                                KV, 1028, 512, 256, 0);
    k_gemm_mfma<<<dim3(6, 94), 256, 0, stream>>>(etgt, ed_qkv_w, ed_qkv_b, eqkv, LEB, 768, 256, 0);
    k_edge_self_attn<<<dim3(255, 4), 256, 0, stream>>>(eqkv, et1);
    k_gemm_ln<<<188, 256, 0, stream>>>(et1, ed_so_w, ed_so_b, etgt, ed_ln_g, ed_ln_b,
                                       nullptr, nullptr, etgt, LEB, 0);
    k_gemm_mfma<<<dim3(2, 94), 256, 0, stream>>>(etgt, ed_cqkv_w, ed_cqkv_b, eqkv, LEB, 256, 256, 0);
    k_edge_cross_attn<<<dim3(LE, 4), 128, 0, stream>>>(eqkv, KV, grp, et1);
    k_gemm_ln<<<188, 256, 0, stream>>>(et1, ed_co_w, ed_co_b, etgt, ed_ln_g + 256, ed_ln_b + 256,
                                       nullptr, nullptr, etgt, LEB, 0);
    k_gemm_mfma<<<dim3(2, 94), 256, 0, stream>>>(etgt, ed_ff1_w, ed_ff1_b, et1, LEB, 256, 256, 1);
    k_gemm_ln<<<188, 256, 0, stream>>>(et1, ed_ff2_w, ed_ff2_b, etgt, ed_ln_g + 512, ed_ln_b + 512,
                                       ed_fn_g, ed_fn_b, etgt, LEB, 1);

    // edge losses
    k_ce_edge<<<512, 256, 0, stream>>>(etgt, ec0_w, ec0_b, ec1_w, ec1_b,
                                       bond_y, LEB, 1.f / (float)LEB, out);
}

// Round 7
// 597.800 us; speedup vs baseline: 1.1954x; 1.1954x over previous
//
#include <hip/hip_runtime.h>
#include <math.h>

#define SS 256
#define BB 4
#define HH 256
#define LE 2994
#define LEB (LE*BB)
#define SCALE 0.08838834764831845f  // 1/sqrt(128)

typedef __attribute__((ext_vector_type(8))) short bf16x8;
typedef __attribute__((ext_vector_type(4))) float f32x4;

__device__ inline ushort f2b(float f) {   // fp32 -> bf16 RNE
    unsigned u = __float_as_uint(f);
    u += 0x7FFFu + ((u >> 16) & 1u);
    return (ushort)(u >> 16);
}

__device__ inline float qred(float x) {   // sum across the 16 lanes of a quarter-wave
    x += __shfl_xor(x, 1); x += __shfl_xor(x, 2);
    x += __shfl_xor(x, 4); x += __shfl_xor(x, 8);
    return x;
}

// ---------------- init: zero loss/bnsums + edge tables ----------------

__global__ void k_init(float* __restrict__ out, float* __restrict__ bnsums,
                       int* __restrict__ grp, int* __restrict__ idxt) {
    int bid = blockIdx.x, t = threadIdx.x;
    if (bid == 0) {
        if (t == 0) out[0] = 0.f;
        bnsums[t] = 0.f; bnsums[256 + t] = 0.f;
        return;
    }
    int e = (bid - 1) * 256 + t;
    if (e >= LE) return;
    int g, pos;
    if (e < 78) {
        g = (int)((1.0f + sqrtf(8.0f * (float)e + 1.0f)) * 0.5f);
        while (g * (g - 1) / 2 > e) g--;
        while ((g + 1) * g / 2 <= e) g++;
        pos = e - g * (g - 1) / 2;
        idxt[e] = pos;
    } else {
        int r = e - 78;
        g = 13 + r / 12;
        pos = r % 12;
        idxt[e] = g - 12 + pos;
    }
    grp[e] = g;
}

// ---------------- weight pre-pack: fp32 W[N][256] -> bf16 MFMA-fragment layout ----------------
// frag (tn,tk) of a matrix: 64 lanes x 8 bf16, lane=( (k>>3)&3 )*16 + (n&15), elem=k&7.
// Global frag id = fs[i] + tn*8 + tk.  dst[frag*512 + lane*8 .. +7].

#define NPACK 14
#define TOTFRAG 2816
struct PackArgs { const float* src[NPACK]; int fs[NPACK + 1]; };

__global__ __launch_bounds__(256) void k_prep(PackArgs pa, ushort* __restrict__ dst) {
    int wid = (blockIdx.x * 256 + threadIdx.x) >> 6;
    int lane = threadIdx.x & 63;
    if (wid >= TOTFRAG) return;
    int i = 0;
    while (pa.fs[i + 1] <= wid) i++;
    int f = wid - pa.fs[i];
    int tn = f >> 3, tk = f & 7;
    int q = lane >> 4, p = lane & 15;
    const float* s = pa.src[i] + (size_t)(tn * 16 + p) * 256 + tk * 32 + q * 8;
    float4 a0 = *(const float4*)s, a1 = *(const float4*)(s + 4);
    uint4 o = make_uint4(f2b(a0.x) | ((unsigned)f2b(a0.y) << 16),
                         f2b(a0.z) | ((unsigned)f2b(a0.w) << 16),
                         f2b(a1.x) | ((unsigned)f2b(a1.y) << 16),
                         f2b(a1.z) | ((unsigned)f2b(a1.w) << 16));
    *(uint4*)&dst[(size_t)wid * 512 + lane * 8] = o;
}

// ---------------- unified bf16 GEMM with packed W, K=256 ----------------
// Block tile 64 rows x 256 cols, 4 waves (wave w = cols w*64..+63). grid (N/256, ceil(M/64)).
// mode 0: C[M,N] = A@W^T + bias (+relu)
// mode 1: C = LN(res + A@W^T + bias)         (requires gridDim.x==1, N=256)
// mode 2: C = LN2(LN(res + A@W^T + bias))    (requires gridDim.x==1, N=256)
// mode 3: node QKV: N=768; cols<512 -> C (stride 768), cols>=512 -> Vt[z][dh][s]

__global__ __launch_bounds__(256) void k_gemm_w(
    const float* __restrict__ A, const ushort* __restrict__ Wp,
    const float* __restrict__ bias, const float* __restrict__ res,
    const float* __restrict__ g1, const float* __restrict__ b1,
    const float* __restrict__ g2, const float* __restrict__ b2,
    float* __restrict__ C, float* __restrict__ Vt,
    int M, int N, int mode, int relu)
{
    __shared__ ushort As[32 * 512];   // 4 mt x 8 kt frags, 32 KB
    int tid = threadIdx.x;
    int w = tid >> 6, lane = tid & 63;
    int q = lane >> 4, p = lane & 15;
    int m0 = blockIdx.y * 64, n0 = blockIdx.x * 256;

    // ---- stage A once: fp32 -> bf16 fragment layout ----
    {
        int r = tid >> 2;
        int cbase = (tid & 3) * 64;
        int gm = m0 + r;
        const float* Ar = A + (size_t)gm * 256 + cbase;
        bool ok = gm < M;
        #pragma unroll
        for (int j = 0; j < 8; j++) {
            int c = cbase + j * 8;
            float4 a0, a1;
            if (ok) { a0 = *(const float4*)(Ar + j * 8); a1 = *(const float4*)(Ar + j * 8 + 4); }
            else { a0 = make_float4(0.f, 0.f, 0.f, 0.f); a1 = a0; }
            uint4 o = make_uint4(f2b(a0.x) | ((unsigned)f2b(a0.y) << 16),
                                 f2b(a0.z) | ((unsigned)f2b(a0.w) << 16),
                                 f2b(a1.x) | ((unsigned)f2b(a1.y) << 16),
                                 f2b(a1.z) | ((unsigned)f2b(a1.w) << 16));
            int frag = (r >> 4) * 8 + (c >> 5);
            int fl = ((c >> 3) & 3) * 16 + (r & 15);
            *(uint4*)&As[frag * 512 + fl * 8] = o;
        }
    }
    __syncthreads();

    f32x4 acc[4][4];
    #pragma unroll
    for (int i = 0; i < 4; i++)
        #pragma unroll
        for (int j = 0; j < 4; j++) acc[i][j] = (f32x4){0.f, 0.f, 0.f, 0.f};

    int nw = n0 + w * 64;
    const ushort* Wb = Wp + (size_t)(nw >> 4) * 4096;   // frag row base: ((nw>>4)+nt)*8 frags

    #pragma unroll
    for (int kt = 0; kt < 8; kt++) {
        bf16x8 afr[4], wfr[4];
        #pragma unroll
        for (int mt = 0; mt < 4; mt++)
            afr[mt] = *(const bf16x8*)&As[(mt * 8 + kt) * 512 + lane * 8];
        #pragma unroll
        for (int nt = 0; nt < 4; nt++)
            wfr[nt] = *(const bf16x8*)&Wb[(size_t)(nt * 8 + kt) * 512 + lane * 8];
        #pragma unroll
        for (int mt = 0; mt < 4; mt++)
            #pragma unroll
            for (int nt = 0; nt < 4; nt++)
                acc[mt][nt] = __builtin_amdgcn_mfma_f32_16x16x32_bf16(afr[mt], wfr[nt], acc[mt][nt], 0, 0, 0);
    }

    if (mode == 0 || mode == 3) {
        float bi[4]; int col[4];
        #pragma unroll
        for (int nt = 0; nt < 4; nt++) { col[nt] = nw + nt * 16 + p; bi[nt] = bias[col[nt]]; }
        #pragma unroll
        for (int mt = 0; mt < 4; mt++)
            #pragma unroll
            for (int reg = 0; reg < 4; reg++) {
                int grow = m0 + mt * 16 + q * 4 + reg;
                if (grow >= M) continue;
                #pragma unroll
                for (int nt = 0; nt < 4; nt++) {
                    float v = acc[mt][nt][reg] + bi[nt];
                    if (relu) v = fmaxf(v, 0.f);
                    if (mode == 3) {
                        if (col[nt] < 512) {
                            C[(size_t)grow * 768 + col[nt]] = v;
                        } else {
                            int hh = (col[nt] - 512) >> 7, dh = (col[nt] - 512) & 127;
                            int zz = (grow & 3) * 2 + hh;
                            Vt[(size_t)zz * 32768 + (size_t)dh * 256 + (grow >> 2)] = v;
                        }
                    } else {
                        C[(size_t)grow * N + col[nt]] = v;
                    }
                }
            }
        return;
    }

    // mode 1/2: residual + LayerNorm (gridDim.x==1, cols = w*64+nt*16+p)
    float bi[4], gg[4], bb[4]; int col[4];
    #pragma unroll
    for (int nt = 0; nt < 4; nt++) {
        col[nt] = w * 64 + nt * 16 + p;
        bi[nt] = bias[col[nt]]; gg[nt] = g1[col[nt]]; bb[nt] = b1[col[nt]];
    }
    #pragma unroll
    for (int mt = 0; mt < 4; mt++)
        #pragma unroll
        for (int reg = 0; reg < 4; reg++) {
            int grow = m0 + mt * 16 + q * 4 + reg;
            bool ok = grow < M;
            #pragma unroll
            for (int nt = 0; nt < 4; nt++)
                acc[mt][nt][reg] += bi[nt] + (ok ? res[(size_t)grow * 256 + col[nt]] : 0.f);
        }
    float* red = (float*)As;
    __syncthreads();   // done with As as fragments
    int passes = (mode == 2) ? 2 : 1;
    for (int pass = 0; pass < passes; pass++) {
        #pragma unroll
        for (int mt = 0; mt < 4; mt++)
            #pragma unroll
            for (int reg = 0; reg < 4; reg++) {
                float s = acc[mt][0][reg] + acc[mt][1][reg] + acc[mt][2][reg] + acc[mt][3][reg];
                s = qred(s);
                if (p == 0) red[w * 64 + mt * 16 + q * 4 + reg] = s;
            }
        __syncthreads();
        if (tid < 64) red[256 + tid] = (red[tid] + red[64 + tid] + red[128 + tid] + red[192 + tid]) * (1.f / 256.f);
        __syncthreads();
        #pragma unroll
        for (int mt = 0; mt < 4; mt++)
            #pragma unroll
            for (int reg = 0; reg < 4; reg++) {
                int lr = mt * 16 + q * 4 + reg;
                float mean = red[256 + lr];
                float sq = 0.f;
                #pragma unroll
                for (int nt = 0; nt < 4; nt++) {
                    acc[mt][nt][reg] -= mean;
                    sq += acc[mt][nt][reg] * acc[mt][nt][reg];
                }
                sq = qred(sq);
                if (p == 0) red[w * 64 + lr] = sq;
            }
        __syncthreads();
        if (tid < 64) red[256 + tid] = rsqrtf((red[tid] + red[64 + tid] + red[128 + tid] + red[192 + tid]) * (1.f / 256.f) + 1e-5f);
        __syncthreads();
        #pragma unroll
        for (int mt = 0; mt < 4; mt++)
            #pragma unroll
            for (int reg = 0; reg < 4; reg++) {
                float rstd = red[256 + mt * 16 + q * 4 + reg];
                #pragma unroll
                for (int nt = 0; nt < 4; nt++)
                    acc[mt][nt][reg] = acc[mt][nt][reg] * rstd * gg[nt] + bb[nt];
            }
        if (pass == 0 && mode == 2) {
            #pragma unroll
            for (int nt = 0; nt < 4; nt++) { gg[nt] = g2[col[nt]]; bb[nt] = b2[col[nt]]; }
            __syncthreads();
        }
    }
    #pragma unroll
    for (int mt = 0; mt < 4; mt++)
        #pragma unroll
        for (int reg = 0; reg < 4; reg++) {
            int grow = m0 + mt * 16 + q * 4 + reg;
            if (grow >= M) continue;
            #pragma unroll
            for (int nt = 0; nt < 4; nt++)
                C[(size_t)grow * 256 + col[nt]] = acc[mt][nt][reg];
        }
}

// ---------------- fused QK^T + scale + causal mask + softmax -> bf16 P ----------------

__global__ __launch_bounds__(256) void k_attn_qks(
    const float* __restrict__ qkv, ushort* __restrict__ P)
{
    __shared__ ushort Qs[64 * 32];
    __shared__ ushort Ks[256 * 32];
    int tid = threadIdx.x;
    int wave = tid >> 6, lane = tid & 63;
    int q = lane >> 4, p = lane & 15;
    int m0 = blockIdx.x * 64;
    int z = blockIdx.y, b = z >> 1, h = z & 1;
    size_t qoff = (size_t)b * 768 + h * 128;

    f32x4 acc[16];
    #pragma unroll
    for (int i = 0; i < 16; i++) acc[i] = (f32x4){0.f, 0.f, 0.f, 0.f};

    int sra = tid >> 2, sca = (tid & 3) << 3;
    const float* Arow = qkv + (size_t)(m0 + sra) * 3072 + qoff + sca;
    const float* Wrow = qkv + (size_t)tid * 3072 + qoff + 256;
    ushort* asd = &Qs[sra * 32 + sca];
    ushort* wsd = &Ks[tid * 32];

    for (int k0 = 0; k0 < 128; k0 += 32) {
        float4 a0 = *(const float4*)(Arow + k0);
        float4 a1 = *(const float4*)(Arow + k0 + 4);
        float av[8] = {a0.x, a0.y, a0.z, a0.w, a1.x, a1.y, a1.z, a1.w};
        float wv[32];
        #pragma unroll
        for (int i = 0; i < 8; i++) {
            float4 w4 = *(const float4*)(Wrow + k0 + i * 4);
            wv[i*4+0] = w4.x; wv[i*4+1] = w4.y; wv[i*4+2] = w4.z; wv[i*4+3] = w4.w;
        }
        unsigned au[4], wu[16];
        #pragma unroll
        for (int i = 0; i < 4; i++) au[i] = (unsigned)f2b(av[2*i]) | ((unsigned)f2b(av[2*i+1]) << 16);
        #pragma unroll
        for (int i = 0; i < 16; i++) wu[i] = (unsigned)f2b(wv[2*i]) | ((unsigned)f2b(wv[2*i+1]) << 16);
        __syncthreads();
        ((uint4*)asd)[0] = make_uint4(au[0], au[1], au[2], au[3]);
        ((uint4*)wsd)[0] = make_uint4(wu[0], wu[1], wu[2], wu[3]);
        ((uint4*)(wsd + 8))[0] = make_uint4(wu[4], wu[5], wu[6], wu[7]);
        ((uint4*)(wsd + 16))[0] = make_uint4(wu[8], wu[9], wu[10], wu[11]);
        ((uint4*)(wsd + 24))[0] = make_uint4(wu[12], wu[13], wu[14], wu[15]);
        __syncthreads();

        bf16x8 af = *(const bf16x8*)&Qs[(wave * 16 + p) * 32 + q * 8];
        #pragma unroll
        for (int nt = 0; nt < 16; nt++) {
            bf16x8 bf = *(const bf16x8*)&Ks[(nt * 16 + p) * 32 + q * 8];
            acc[nt] = __builtin_amdgcn_mfma_f32_16x16x32_bf16(af, bf, acc[nt], 0, 0, 0);
        }
    }

    ushort* Pz = P + (size_t)z * 65536;
    #pragma unroll
    for (int reg = 0; reg < 4; reg++) {
        int row = m0 + wave * 16 + q * 4 + reg;
        float v[16]; float mx = -1e30f;
        #pragma unroll
        for (int nt = 0; nt < 16; nt++) {
            int colk = nt * 16 + p;
            float val = (colk <= row) ? acc[nt][reg] * SCALE : -1e30f;
            v[nt] = val; mx = fmaxf(mx, val);
        }
        mx = fmaxf(mx, __shfl_xor(mx, 1)); mx = fmaxf(mx, __shfl_xor(mx, 2));
        mx = fmaxf(mx, __shfl_xor(mx, 4)); mx = fmaxf(mx, __shfl_xor(mx, 8));
        float s = 0.f;
        #pragma unroll
        for (int nt = 0; nt < 16; nt++) {
            int colk = nt * 16 + p;
            float e = (colk <= row) ? __expf(v[nt] - mx) : 0.f;
            v[nt] = e; s += e;
        }
        s += __shfl_xor(s, 1); s += __shfl_xor(s, 2); s += __shfl_xor(s, 4); s += __shfl_xor(s, 8);
        float inv = 1.f / s;
        #pragma unroll
        for (int nt = 0; nt < 16; nt++)
            Pz[(size_t)row * 256 + nt * 16 + p] = f2b(v[nt] * inv);
    }
}

// ---------------- PV: O = P @ V ----------------

__global__ __launch_bounds__(256) void k_attn_pvt(
    const ushort* __restrict__ P, const float* __restrict__ Vt,
    float* __restrict__ out)
{
    __shared__ ushort As[64 * 32];
    __shared__ ushort Bs[128 * 32];
    int tid = threadIdx.x;
    int wave = tid >> 6, lane = tid & 63;
    int q = lane >> 4, p = lane & 15;
    int m0 = blockIdx.x * 64;
    int z = blockIdx.y, b = z >> 1, h = z & 1;

    f32x4 acc[8];
    #pragma unroll
    for (int i = 0; i < 8; i++) acc[i] = (f32x4){0.f, 0.f, 0.f, 0.f};

    int sra = tid >> 2, sca = (tid & 3) << 3;
    const ushort* Prow = P + (size_t)z * 65536 + (size_t)(m0 + sra) * 256 + sca;
    int srb = tid >> 1, scb = (tid & 1) << 4;
    const float* Vrow = Vt + (size_t)z * 32768 + (size_t)srb * 256 + scb;
    ushort* asd = &As[sra * 32 + sca];
    ushort* wsd = &Bs[srb * 32 + scb];

    for (int k0 = 0; k0 < 256; k0 += 32) {
        uint4 pa = *(const uint4*)(Prow + k0);
        float wv[16];
        #pragma unroll
        for (int i = 0; i < 4; i++) {
            float4 w4 = *(const float4*)(Vrow + k0 + i * 4);
            wv[i*4+0] = w4.x; wv[i*4+1] = w4.y; wv[i*4+2] = w4.z; wv[i*4+3] = w4.w;
        }
        unsigned wu[8];
        #pragma unroll
        for (int i = 0; i < 8; i++) wu[i] = (unsigned)f2b(wv[2*i]) | ((unsigned)f2b(wv[2*i+1]) << 16);
        __syncthreads();
        ((uint4*)asd)[0] = pa;
        ((uint4*)wsd)[0] = make_uint4(wu[0], wu[1], wu[2], wu[3]);
        ((uint4*)(wsd + 8))[0] = make_uint4(wu[4], wu[5], wu[6], wu[7]);
        __syncthreads();

        bf16x8 af = *(const bf16x8*)&As[(wave * 16 + p) * 32 + q * 8];
        #pragma unroll
        for (int nt = 0; nt < 8; nt++) {
            bf16x8 bf = *(const bf16x8*)&Bs[(nt * 16 + p) * 32 + q * 8];
            acc[nt] = __builtin_amdgcn_mfma_f32_16x16x32_bf16(af, bf, acc[nt], 0, 0, 0);
        }
    }

    #pragma unroll
    for (int reg = 0; reg < 4; reg++) {
        int s = m0 + wave * 16 + q * 4 + reg;
        #pragma unroll
        for (int nt = 0; nt < 8; nt++) {
            int dh = nt * 16 + p;
            out[(size_t)s * 1024 + (size_t)b * 256 + h * 128 + dh] = acc[nt][reg];
        }
    }
}

// ---------------- generic fp32 GEMM (input projection K=54 only) ----------------

__global__ __launch_bounds__(256) void k_gemm(
    const float* __restrict__ A, const float* __restrict__ W,
    const float* __restrict__ bias, float* __restrict__ C,
    int M, int N, int K, int relu)
{
    __shared__ __align__(16) float As[16][68];
    __shared__ __align__(16) float Ws[16][68];
    int tx = threadIdx.x, ty = threadIdx.y;
    int tid = ty * 16 + tx;
    int m0 = blockIdx.y * 64, n0 = blockIdx.x * 64;
    float acc[4][4] = {{0.f}};
    int r  = tid >> 2;
    int kk = (tid & 3) << 2;
    for (int k0 = 0; k0 < K; k0 += 16) {
        float4 av = make_float4(0.f, 0.f, 0.f, 0.f);
        float4 wv = make_float4(0.f, 0.f, 0.f, 0.f);
        int gm = m0 + r, gk = k0 + kk;
        if (gm < M) {
            float tv[4];
            for (int i = 0; i < 4; i++) tv[i] = (gk + i < K) ? A[(size_t)gm * K + gk + i] : 0.f;
            av = make_float4(tv[0], tv[1], tv[2], tv[3]);
        }
        int gn = n0 + r;
        if (gn < N) {
            float tv[4];
            for (int i = 0; i < 4; i++) tv[i] = (gk + i < K) ? W[(size_t)gn * K + gk + i] : 0.f;
            wv = make_float4(tv[0], tv[1], tv[2], tv[3]);
        }
        As[kk + 0][r] = av.x; As[kk + 1][r] = av.y; As[kk + 2][r] = av.z; As[kk + 3][r] = av.w;
        Ws[kk + 0][r] = wv.x; Ws[kk + 1][r] = wv.y; Ws[kk + 2][r] = wv.z; Ws[kk + 3][r] = wv.w;
        __syncthreads();
        #pragma unroll
        for (int k = 0; k < 16; k++) {
            float4 a4 = *(const float4*)&As[k][ty << 2];
            float4 b4 = *(const float4*)&Ws[k][tx << 2];
            float a[4] = {a4.x, a4.y, a4.z, a4.w};
            float b[4] = {b4.x, b4.y, b4.z, b4.w};
            #pragma unroll
            for (int i = 0; i < 4; i++)
                #pragma unroll
                for (int j = 0; j < 4; j++)
                    acc[i][j] = fmaf(a[i], b[j], acc[i][j]);
        }
        __syncthreads();
    }
    #pragma unroll
    for (int i = 0; i < 4; i++) {
        int gm = m0 + (ty << 2) + i;
        if (gm >= M) continue;
        #pragma unroll
        for (int j = 0; j < 4; j++) {
            int gn = n0 + (tx << 2) + j;
            if (gn >= N) continue;
            float v = acc[i][j] + bias[gn];
            if (relu) v = fmaxf(v, 0.f);
            C[(size_t)gm * N + gn] = v;
        }
    }
}

// ---------------- residual + LayerNorm (mode 1: broadcast delta) ----------------

__global__ __launch_bounds__(256) void k_add_ln(
    const float* __restrict__ x, const float* __restrict__ delta,
    const float* __restrict__ g, const float* __restrict__ bta,
    float* __restrict__ out, int M, int mode)
{
    int row = blockIdx.x * 4 + (threadIdx.x >> 6);
    int t = threadIdx.x & 63;
    if (row >= M) return;
    float4 v = ((const float4*)(x + (size_t)row * HH))[t];
    if (mode == 0) {
        float4 d = ((const float4*)(delta + (size_t)row * HH))[t];
        v.x += d.x; v.y += d.y; v.z += d.z; v.w += d.w;
    } else if (mode == 1) {
        float4 d = ((const float4*)(delta + (size_t)(row & 3) * HH))[t];
        v.x += d.x; v.y += d.y; v.z += d.z; v.w += d.w;
    }
    float s = v.x + v.y + v.z + v.w;
    for (int o = 32; o; o >>= 1) s += __shfl_down(s, o);
    float mean = __shfl(s, 0) * (1.f / 256.f);
    float cx = v.x - mean, cy = v.y - mean, cz = v.z - mean, cw = v.w - mean;
    float q = cx * cx + cy * cy + cz * cz + cw * cw;
    for (int o = 32; o; o >>= 1) q += __shfl_down(q, o);
    float rstd = rsqrtf(__shfl(q, 0) * (1.f / 256.f) + 1e-5f);
    float4 gg = ((const float4*)g)[t];
    float4 bb = ((const float4*)bta)[t];
    float4 o4;
    o4.x = cx * rstd * gg.x + bb.x;
    o4.y = cy * rstd * gg.y + bb.y;
    o4.z = cz * rstd * gg.z + bb.z;
    o4.w = cw * rstd * gg.w + bb.w;
    ((float4*)(out + (size_t)row * HH))[t] = o4;
}

// ---------------- BatchNorm partial sums ----------------

__global__ __launch_bounds__(256) void k_bn_part(const float* __restrict__ x, float* __restrict__ sums) {
    int t = threadIdx.x;
    int r0 = blockIdx.x * 16;
    float s = 0.f, s2 = 0.f;
    for (int r = r0; r < r0 + 16; r++) {
        float v = x[(size_t)r * 256 + t];
        s += v; s2 += v * v;
    }
    atomicAdd(&sums[t], s);
    atomicAdd(&sums[256 + t], s2);
}

// ---------------- BN-finalize + SELU + positional encoding ----------------

__global__ __launch_bounds__(256) void k_bn_selu_pe(
    const float* __restrict__ x0, const float* __restrict__ sums,
    const float* __restrict__ g, const float* __restrict__ b,
    const int* __restrict__ atom_i, float* __restrict__ out)
{
    int row = blockIdx.x, t = threadIdx.x;
    float m = sums[t] * (1.f / 1024.f);
    float var = sums[256 + t] * (1.f / 1024.f) - m * m;
    float rstd = rsqrtf(var + 1e-5f);
    float v = x0[(size_t)row * 256 + t];
    v = (v - m) * rstd * g[t] + b[t];
    const float SC = 1.0507009873554805f, AL = 1.6732632423543772f;
    v = SC * (v > 0.f ? v : AL * expm1f(v));
    float pos = (float)atom_i[row];
    float freq = expf(-(float)t * (9.210340371976184f / 256.f));
    float ang = pos * freq;
    float pe = (t & 1) ? cosf(ang) : sinf(ang);
    out[(size_t)row * 256 + t] = v + pe;
}

// ---------------- both-layer node cross-attn constant ----------------

__global__ __launch_bounds__(256) void k_cross2(
    const float* __restrict__ z, const float* __restrict__ cqkv_w, const float* __restrict__ cqkv_b,
    const float* __restrict__ co_w, const float* __restrict__ co_b, float* __restrict__ crO)
{
    int m = blockIdx.x, l = blockIdx.y;
    int t = threadIdx.x;
    __shared__ float zs[256], ct[256];
    zs[t] = z[m * 256 + t];
    __syncthreads();
    const float* wv = cqkv_w + (size_t)l * 768 * 256 + 512 * 256 + (size_t)t * 256;
    float a = cqkv_b[l * 768 + 512 + t];
    for (int d = 0; d < 256; d += 4) {
        float4 w4 = *(const float4*)(wv + d);
        a += zs[d] * w4.x + zs[d+1] * w4.y + zs[d+2] * w4.z + zs[d+3] * w4.w;
    }
    ct[t] = a;
    __syncthreads();
    const float* ow = co_w + (size_t)l * 65536 + (size_t)t * 256;
    float o = co_b[l * 256 + t];
    for (int d = 0; d < 256; d += 4) {
        float4 w4 = *(const float4*)(ow + d);
        o += ct[d] * w4.x + ct[d+1] * w4.y + ct[d+2] * w4.z + ct[d+3] * w4.w;
    }
    crO[l * 1024 + m * 256 + t] = o;
}

// ---------------- edge group self-attention ----------------

__global__ __launch_bounds__(256) void k_edge_self_attn(
    const float* __restrict__ qkv, float* __restrict__ out)
{
    int g = blockIdx.x + 1;
    int b = blockIdx.y;
    int gs = min(g, 12);
    int base = (g <= 13) ? g * (g - 1) / 2 : 78 + (g - 13) * 12;
    int h = threadIdx.x >> 7;
    int t = threadIdx.x & 127;
    __shared__ float qs[2][12][128], ks[2][12][128], vs[2][12][128];
    __shared__ float ps[2][12][12];
    for (int i = 0; i < gs; i++) {
        size_t row = ((size_t)(base + i) * BB + b) * 768 + h * 128 + t;
        qs[h][i][t] = qkv[row];
        ks[h][i][t] = qkv[row + 256];
        vs[h][i][t] = qkv[row + 512];
    }
    __syncthreads();
    for (int p = t; p < gs * gs; p += 128) {
        int i = p / gs, j = p - i * gs;
        float acc = 0.f;
        for (int d = 0; d < 128; d++) acc = fmaf(qs[h][i][d], ks[h][j][d], acc);
        ps[h][i][j] = acc * SCALE;
    }
    __syncthreads();
    if (t < gs) {
        float m = -1e30f;
        for (int j = 0; j < gs; j++) m = fmaxf(m, ps[h][t][j]);
        float e[12]; float s = 0.f;
        for (int j = 0; j < gs; j++) { e[j] = expf(ps[h][t][j] - m); s += e[j]; }
        float inv = 1.f / s;
        for (int j = 0; j < gs; j++) ps[h][t][j] = e[j] * inv;
    }
    __syncthreads();
    for (int i = 0; i < gs; i++) {
        float acc = 0.f;
        for (int j = 0; j < gs; j++) acc = fmaf(ps[h][i][j], vs[h][j][t], acc);
        out[((size_t)(base + i) * BB + b) * 256 + h * 128 + t] = acc;
    }
}

// ---------------- edge 2-key cross-attention ----------------

__global__ __launch_bounds__(128) void k_edge_cross_attn(
    const float* __restrict__ Q, const float* __restrict__ KV,
    const int* __restrict__ grp, float* __restrict__ out)
{
    int e = blockIdx.x, b = blockIdx.y;
    int h = threadIdx.x >> 6, l = threadIdx.x & 63;
    int g = grp[e];
    size_t qrow = ((size_t)e * BB + b) * 256 + h * 128;
    float qa = Q[qrow + l], qb = Q[qrow + 64 + l];
    size_t k0r = (size_t)b * 512 + h * 128;
    size_t k1r = ((size_t)(g + 1) * BB + b) * 512 + h * 128;
    float p0 = qa * KV[k0r + l] + qb * KV[k0r + 64 + l];
    float p1 = qa * KV[k1r + l] + qb * KV[k1r + 64 + l];
    for (int o = 32; o; o >>= 1) { p0 += __shfl_down(p0, o); p1 += __shfl_down(p1, o); }
    p0 = __shfl(p0, 0) * SCALE;
    p1 = __shfl(p1, 0) * SCALE;
    float m = fmaxf(p0, p1);
    float e0 = expf(p0 - m), e1 = expf(p1 - m);
    float inv = 1.f / (e0 + e1);
    e0 *= inv; e1 *= inv;
    out[qrow + l]      = e0 * KV[k0r + 256 + l]      + e1 * KV[k1r + 256 + l];
    out[qrow + 64 + l] = e0 * KV[k0r + 256 + 64 + l] + e1 * KV[k1r + 256 + 64 + l];
}

// ---------------- gather + build_mem fused ----------------

__global__ __launch_bounds__(256) void k_gather_mem(
    const float* __restrict__ z, const float* __restrict__ nemb,
    const int* __restrict__ idxt, float* __restrict__ etgt, float* __restrict__ memb)
{
    int r = blockIdx.x, t = threadIdx.x;
    if (r < LEB) {
        int e = r >> 2, b = r & 3;
        etgt[(size_t)r * 256 + t] = nemb[((size_t)idxt[e] * 4 + b) * 256 + t];
    } else {
        int rm = r - LEB;
        int m = rm >> 2, b = rm & 3;
        memb[(size_t)rm * 256 + t] = (m == 0) ? z[(size_t)b * 256 + t]
                                              : nemb[((size_t)(m - 1) * 4 + b) * 256 + t];
    }
}

// ---------------- fused cross-entropy ----------------

__global__ __launch_bounds__(256) void k_ce_node(
    const float* __restrict__ emb,
    const float* __restrict__ w0, const float* __restrict__ b0,
    const float* __restrict__ w1, const float* __restrict__ b1,
    const float* __restrict__ w2, const float* __restrict__ b2,
    const int* __restrict__ y, int M, float invM, float* __restrict__ lossOut)
{
    int wave = threadIdx.x >> 6, lane = threadIdx.x & 63;
    int wid = blockIdx.x * 4 + wave;
    float local = 0.f;
    for (int r = wid; r < M; r += gridDim.x * 4) {
        float4 x = ((const float4*)(emb + (size_t)r * 256))[lane];
        float acc[54];
        #pragma unroll
        for (int c = 0; c < 40; c++) {
            float4 wv = ((const float4*)(w0 + (size_t)c * 256))[lane];
            acc[c] = x.x * wv.x + x.y * wv.y + x.z * wv.z + x.w * wv.w;
        }
        #pragma unroll
        for (int c = 0; c < 8; c++) {
            float4 wv = ((const float4*)(w1 + (size_t)c * 256))[lane];
            acc[40 + c] = x.x * wv.x + x.y * wv.y + x.z * wv.z + x.w * wv.w;
        }
        #pragma unroll
        for (int c = 0; c < 6; c++) {
            float4 wv = ((const float4*)(w2 + (size_t)c * 256))[lane];
            acc[48 + c] = x.x * wv.x + x.y * wv.y + x.z * wv.z + x.w * wv.w;
        }
        #pragma unroll
        for (int c = 0; c < 54; c++)
            for (int o = 32; o; o >>= 1) acc[c] += __shfl_down(acc[c], o);
        if (lane == 0) {
            int y0 = y[(size_t)r * 3 + 0], y1 = y[(size_t)r * 3 + 1], y2 = y[(size_t)r * 3 + 2];
            float m0 = -1e30f, m1 = -1e30f, m2 = -1e30f;
            float lg[54];
            for (int c = 0; c < 40; c++) { lg[c] = acc[c] + b0[c]; m0 = fmaxf(m0, lg[c]); }
            for (int c = 0; c < 8; c++)  { lg[40 + c] = acc[40 + c] + b1[c]; m1 = fmaxf(m1, lg[40 + c]); }
            for (int c = 0; c < 6; c++)  { lg[48 + c] = acc[48 + c] + b2[c]; m2 = fmaxf(m2, lg[48 + c]); }
            float s0 = 0.f, s1 = 0.f, s2 = 0.f;
            for (int c = 0; c < 40; c++) s0 += expf(lg[c] - m0);
            for (int c = 0; c < 8; c++)  s1 += expf(lg[40 + c] - m1);
            for (int c = 0; c < 6; c++)  s2 += expf(lg[48 + c] - m2);
            local += (m0 + logf(s0) - lg[y0]) + (m1 + logf(s1) - lg[40 + y1]) + (m2 + logf(s2) - lg[48 + y2]);
        }
    }
    __shared__ float ls[4];
    if (lane == 0) ls[wave] = local;
    __syncthreads();
    if (threadIdx.x == 0)
        atomicAdd(lossOut, (ls[0] + ls[1] + ls[2] + ls[3]) * invM);
}

__global__ __launch_bounds__(256) void k_ce_edge(
    const float* __restrict__ emb,
    const float* __restrict__ w0, const float* __restrict__ b0,
    const float* __restrict__ w1, const float* __restrict__ b1,
    const int* __restrict__ y, int M, float invM, float* __restrict__ lossOut)
{
    int wave = threadIdx.x >> 6, lane = threadIdx.x & 63;
    int wid = blockIdx.x * 4 + wave;
    float local = 0.f;
    for (int r = wid; r < M; r += gridDim.x * 4) {
        float4 x = ((const float4*)(emb + (size_t)r * 256))[lane];
        float acc[9];
        #pragma unroll
        for (int c = 0; c < 5; c++) {
            float4 wv = ((const float4*)(w0 + (size_t)c * 256))[lane];
            acc[c] = x.x * wv.x + x.y * wv.y + x.z * wv.z + x.w * wv.w;
        }
        #pragma unroll
        for (int c = 0; c < 4; c++) {
            float4 wv = ((const float4*)(w1 + (size_t)c * 256))[lane];
            acc[5 + c] = x.x * wv.x + x.y * wv.y + x.z * wv.z + x.w * wv.w;
        }
        #pragma unroll
        for (int c = 0; c < 9; c++)
            for (int o = 32; o; o >>= 1) acc[c] += __shfl_down(acc[c], o);
        if (lane == 0) {
            int y0 = y[(size_t)r * 2 + 0], y1 = y[(size_t)r * 2 + 1];
            float lg[9];
            float m0 = -1e30f, m1 = -1e30f;
            for (int c = 0; c < 5; c++) { lg[c] = acc[c] + b0[c]; m0 = fmaxf(m0, lg[c]); }
            for (int c = 0; c < 4; c++) { lg[5 + c] = acc[5 + c] + b1[c]; m1 = fmaxf(m1, lg[5 + c]); }
            float s0 = 0.f, s1 = 0.f;
            for (int c = 0; c < 5; c++) s0 += expf(lg[c] - m0);
            for (int c = 0; c < 4; c++) s1 += expf(lg[5 + c] - m1);
            local += (m0 + logf(s0) - lg[y0]) + (m1 + logf(s1) - lg[5 + y1]);
        }
    }
    __shared__ float ls[4];
    if (lane == 0) ls[wave] = local;
    __syncthreads();
    if (threadIdx.x == 0)
        atomicAdd(lossOut, (ls[0] + ls[1] + ls[2] + ls[3]) * invM);
}

// ---------------- host ----------------

extern "C" void kernel_launch(void* const* d_in, const int* in_sizes, int n_in,
                              void* d_out, int out_size, void* d_ws, size_t ws_size,
                              hipStream_t stream)
{
    (void)in_sizes; (void)n_in; (void)out_size; (void)ws_size;
    const float* zin      = (const float*)d_in[0];
    const int*   atom_i   = (const int*)d_in[1];
    const float* atom_x   = (const float*)d_in[2];
    const int*   atom_y   = (const int*)d_in[3];
    const int*   bond_y   = (const int*)d_in[4];
    const float* Wp       = (const float*)d_in[5];
    const float* bp       = (const float*)d_in[6];
    const float* bn_g     = (const float*)d_in[7];
    const float* bn_b     = (const float*)d_in[8];
    const float* nd_qkv_w = (const float*)d_in[9];
    const float* nd_qkv_b = (const float*)d_in[10];
    const float* nd_so_w  = (const float*)d_in[11];
    const float* nd_so_b  = (const float*)d_in[12];
    const float* nd_cqkv_w= (const float*)d_in[13];
    const float* nd_cqkv_b= (const float*)d_in[14];
    const float* nd_co_w  = (const float*)d_in[15];
    const float* nd_co_b  = (const float*)d_in[16];
    const float* nd_ff1_w = (const float*)d_in[17];
    const float* nd_ff1_b = (const float*)d_in[18];
    const float* nd_ff2_w = (const float*)d_in[19];
    const float* nd_ff2_b = (const float*)d_in[20];
    const float* nd_ln_g  = (const float*)d_in[21];
    const float* nd_ln_b  = (const float*)d_in[22];
    const float* nd_fn_g  = (const float*)d_in[23];
    const float* nd_fn_b  = (const float*)d_in[24];
    const float* ed_qkv_w = (const float*)d_in[25];
    const float* ed_qkv_b = (const float*)d_in[26];
    const float* ed_so_w  = (const float*)d_in[27];
    const float* ed_so_b  = (const float*)d_in[28];
    const float* ed_cqkv_w= (const float*)d_in[29];
    const float* ed_cqkv_b= (const float*)d_in[30];
    const float* ed_co_w  = (const float*)d_in[31];
    const float* ed_co_b  = (const float*)d_in[32];
    const float* ed_ff1_w = (const float*)d_in[33];
    const float* ed_ff1_b = (const float*)d_in[34];
    const float* ed_ff2_w = (const float*)d_in[35];
    const float* ed_ff2_b = (const float*)d_in[36];
    const float* ed_ln_g  = (const float*)d_in[37];
    const float* ed_ln_b  = (const float*)d_in[38];
    const float* ed_fn_g  = (const float*)d_in[39];
    const float* ed_fn_b  = (const float*)d_in[40];
    const float* nc0_w = (const float*)d_in[41]; const float* nc0_b = (const float*)d_in[42];
    const float* nc1_w = (const float*)d_in[43]; const float* nc1_b = (const float*)d_in[44];
    const float* nc2_w = (const float*)d_in[45]; const float* nc2_b = (const float*)d_in[46];
    const float* ec0_w = (const float*)d_in[47]; const float* ec0_b = (const float*)d_in[48];
    const float* ec1_w = (const float*)d_in[49]; const float* ec1_b = (const float*)d_in[50];

    float* out = (float*)d_out;

    char* wsb = (char*)d_ws;
    size_t off = 0;
    auto alloc = [&](size_t nbytes) -> void* {
        void* p = (void*)(wsb + off);
        off += (nbytes + 255) / 256 * 256;
        return p;
    };
    float* x0    = (float*)alloc(1024 * 256 * 4);
    float* tgt   = (float*)alloc(1024 * 256 * 4);
    float* nqkv  = (float*)alloc(1024 * 768 * 4);
    float* t1    = (float*)alloc(1024 * 256 * 4);
    float* nemb  = (float*)alloc(1024 * 256 * 4);
    float* bnsums= (float*)alloc(512 * 4);
    float* crO   = (float*)alloc(2 * 1024 * 4);
    float* memb  = (float*)alloc(1028 * 256 * 4);
    float* KV    = (float*)alloc(1028 * 512 * 4);
    ushort* Sb   = (ushort*)alloc(8 * 65536 * 2);
    float* Vt    = (float*)alloc(8 * 32768 * 4);
    float* etgt  = (float*)alloc((size_t)LEB * 256 * 4);
    float* eqkv  = (float*)alloc((size_t)LEB * 768 * 4);
    float* et1   = (float*)alloc((size_t)LEB * 256 * 4);
    int* grp   = (int*)alloc(LE * 4);
    int* idxt  = (int*)alloc(LE * 4);
    ushort* wpk = (ushort*)alloc((size_t)TOTFRAG * 512 * 2);   // packed bf16 weights

    // pack descriptor: 14 matrices, K=256, frag counts: N=768 -> 384, N=256 -> 128
    PackArgs pa;
    pa.src[0] = nd_qkv_w;              pa.src[1] = nd_qkv_w + 768 * 256;
    pa.src[2] = nd_so_w;               pa.src[3] = nd_so_w + 65536;
    pa.src[4] = nd_ff1_w;              pa.src[5] = nd_ff1_w + 65536;
    pa.src[6] = nd_ff2_w;              pa.src[7] = nd_ff2_w + 65536;
    pa.src[8] = ed_qkv_w;              pa.src[9] = ed_cqkv_w;
    pa.src[10] = ed_so_w;              pa.src[11] = ed_co_w;
    pa.src[12] = ed_ff1_w;             pa.src[13] = ed_ff2_w;
    int fs[NPACK + 1] = {0, 384, 768, 896, 1024, 1152, 1280, 1408, 1536, 1920, 2304, 2432, 2560, 2688, 2816};
    for (int i = 0; i <= NPACK; i++) pa.fs[i] = fs[i];
    auto wp = [&](int i) -> const ushort* { return wpk + (size_t)fs[i] * 512; };

    k_init<<<13, 256, 0, stream>>>(out, bnsums, grp, idxt);
    k_prep<<<(TOTFRAG * 64 + 255) / 256, 256, 0, stream>>>(pa, wpk);

    // node input: projection + BN(training stats) + SELU + positional encoding
    k_gemm<<<dim3(4, 16), dim3(16, 16), 0, stream>>>(atom_x, Wp, bp, x0, 1024, 256, 54, 0);
    k_bn_part<<<64, 256, 0, stream>>>(x0, bnsums);
    k_bn_selu_pe<<<1024, 256, 0, stream>>>(x0, bnsums, bn_g, bn_b, atom_i, tgt);

    // both layers' cross-attn constant (depends only on z)
    k_cross2<<<dim3(4, 2), 256, 0, stream>>>(zin, nd_cqkv_w, nd_cqkv_b, nd_co_w, nd_co_b, crO);

    // node decoder: 2 layers
    for (int l = 0; l < 2; l++) {
        // QKV (mode 3: Q,K -> nqkv, V -> Vt)
        k_gemm_w<<<dim3(3, 16), 256, 0, stream>>>(tgt, wp(l), nd_qkv_b + l * 768,
                                                  nullptr, nullptr, nullptr, nullptr, nullptr,
                                                  nqkv, Vt, 1024, 768, 3, 0);
        k_attn_qks<<<dim3(4, 8), 256, 0, stream>>>(nqkv, Sb);
        k_attn_pvt<<<dim3(4, 8), 256, 0, stream>>>(Sb, Vt, t1);
        // self-out + residual + LN
        k_gemm_w<<<dim3(1, 16), 256, 0, stream>>>(t1, wp(2 + l), nd_so_b + l * 256,
                                                  tgt, nd_ln_g + (l * 3 + 0) * 256, nd_ln_b + (l * 3 + 0) * 256,
                                                  nullptr, nullptr, tgt, nullptr, 1024, 256, 1, 0);
        k_add_ln<<<256, 256, 0, stream>>>(tgt, crO + l * 1024,
                                          nd_ln_g + (l * 3 + 1) * 256, nd_ln_b + (l * 3 + 1) * 256,
                                          tgt, 1024, 1);
        // FF1 (relu)
        k_gemm_w<<<dim3(1, 16), 256, 0, stream>>>(tgt, wp(4 + l), nd_ff1_b + l * 256,
                                                  nullptr, nullptr, nullptr, nullptr, nullptr,
                                                  t1, nullptr, 1024, 256, 0, 1);
        // FF2 + residual + LN (+final LN on last layer)
        if (l == 0) {
            k_gemm_w<<<dim3(1, 16), 256, 0, stream>>>(t1, wp(6), nd_ff2_b,
                                                      tgt, nd_ln_g + 2 * 256, nd_ln_b + 2 * 256,
                                                      nullptr, nullptr, tgt, nullptr, 1024, 256, 1, 0);
        } else {
            k_gemm_w<<<dim3(1, 16), 256, 0, stream>>>(t1, wp(7), nd_ff2_b + 256,
                                                      tgt, nd_ln_g + 5 * 256, nd_ln_b + 5 * 256,
                                                      nd_fn_g, nd_fn_b, nemb, nullptr, 1024, 256, 2, 0);
        }
    }

    // node losses
    k_ce_node<<<128, 256, 0, stream>>>(nemb, nc0_w, nc0_b, nc1_w, nc1_b, nc2_w, nc2_b,
                                       atom_y, 1024, 1.f / 1024.f, out);

    // edge path
    k_gather_mem<<<LEB + 1028, 256, 0, stream>>>(zin, nemb, idxt, etgt, memb);
    // KV of edge memory: rows 256..767 of ed_cqkv -> frag offset 128 within matrix 9
    k_gemm_w<<<dim3(2, 17), 256, 0, stream>>>(memb, wp(9) + 128 * 512, ed_cqkv_b + 256,
                                              nullptr, nullptr, nullptr, nullptr, nullptr,
                                              KV, nullptr, 1028, 512, 0, 0);
    // edge self QKV
    k_gemm_w<<<dim3(3, 188), 256, 0, stream>>>(etgt, wp(8), ed_qkv_b,
                                               nullptr, nullptr, nullptr, nullptr, nullptr,
                                               eqkv, nullptr, LEB, 768, 0, 0);
    k_edge_self_attn<<<dim3(255, 4), 256, 0, stream>>>(eqkv, et1);
    k_gemm_w<<<dim3(1, 188), 256, 0, stream>>>(et1, wp(10), ed_so_b,
                                               etgt, ed_ln_g, ed_ln_b, nullptr, nullptr,
                                               etgt, nullptr, LEB, 256, 1, 0);
    // edge cross q projection: rows 0..255 of ed_cqkv
    k_gemm_w<<<dim3(1, 188), 256, 0, stream>>>(etgt, wp(9), ed_cqkv_b,
                                               nullptr, nullptr, nullptr, nullptr, nullptr,
                                               eqkv, nullptr, LEB, 256, 0, 0);
    k_edge_cross_attn<<<dim3(LE, 4), 128, 0, stream>>>(eqkv, KV, grp, et1);
    k_gemm_w<<<dim3(1, 188), 256, 0, stream>>>(et1, wp(11), ed_co_b,
                                               etgt, ed_ln_g + 256, ed_ln_b + 256, nullptr, nullptr,
                                               etgt, nullptr, LEB, 256, 1, 0);
    k_gemm_w<<<dim3(1, 188), 256, 0, stream>>>(etgt, wp(12), ed_ff1_b,
                                               nullptr, nullptr, nullptr, nullptr, nullptr,
                                               et1, nullptr, LEB, 256, 0, 1);
    k_gemm_w<<<dim3(1, 188), 256, 0, stream>>>(et1, wp(13), ed_ff2_b,
                                               etgt, ed_ln_g + 512, ed_ln_b + 512, ed_fn_g, ed_fn_b,
                                               etgt, nullptr, LEB, 256, 2, 0);

    // edge losses
    k_ce_edge<<<512, 256, 0, stream>>>(etgt, ec0_w, ec0_b, ec1_w, ec1_b,
                                       bond_y, LEB, 1.f / (float)LEB, out);
}